// Round 11
// baseline (539.965 us; speedup 1.0000x reference)
//
#include <hip/hip_runtime.h>
#include <hip/hip_bf16.h>
#include <hip/hip_fp16.h>

// Problem constants
constexpr int B = 4, C = 128, T = 512, F = 128, H = 4, D = 64, DV = 32;
constexpr int E  = D * F;   // 8192
constexpr int EV = DV * F;  // 4096
constexpr float EPS = 1e-5f;

// Layouts: qf/kf d-major [b][h][t][d*128+f]; vf/pv f-major [b][h][t][f*32+dv].
// attn logit partials fp16 (kchunks=2). Residual read from bf16 xT.

typedef __attribute__((ext_vector_type(4))) float f32x4;
typedef __attribute__((ext_vector_type(8))) short bf16x8;

__device__ __forceinline__ float bf2f(unsigned short u) {
  return __uint_as_float(((unsigned int)u) << 16);
}
__device__ __forceinline__ unsigned short f2bf(float f) {
  unsigned int b = __float_as_uint(f);
  unsigned int r = b + 0x7FFFu + ((b >> 16) & 1u);
  return (unsigned short)(r >> 16);
}
__device__ __forceinline__ unsigned short f2h(float f) {
  __half h = __float2half(f);
  return __half_as_ushort(h);
}
__device__ __forceinline__ float h2f(unsigned short u) {
  return __half2float(__ushort_as_half(u));
}

__device__ __forceinline__ void gl_lds16(const unsigned short* g, unsigned short* l) {
  __builtin_amdgcn_global_load_lds(
      (const __attribute__((address_space(1))) unsigned int*)(g),
      (__attribute__((address_space(3))) unsigned int*)(l), 16, 0, 0);
}

// ---------------------------------------------------------------------------
// Pack weights: Wall bf16, Wo2 bf16, ball/aall, lwb2[gm][f][2] (lw,lb pairs),
// lwI/lbI interleaved v-tables, lob2[d*128+f][2] (outproj lw,lb pairs).
__global__ __launch_bounds__(256) void prep_kernel(
    const float* __restrict__ Wq, const float* __restrict__ Wk,
    const float* __restrict__ Wv, const float* __restrict__ Wo,
    const float* __restrict__ bq, const float* __restrict__ bk,
    const float* __restrict__ bv, const float* __restrict__ aq,
    const float* __restrict__ ak, const float* __restrict__ av,
    const float* __restrict__ lwq, const float* __restrict__ lwk,
    const float* __restrict__ lwv, const float* __restrict__ lbq,
    const float* __restrict__ lbk, const float* __restrict__ lbv,
    const float* __restrict__ lwo, const float* __restrict__ lbo,
    unsigned short* __restrict__ Wall, unsigned short* __restrict__ Wo2,
    float* __restrict__ ball, float* __restrict__ aall,
    float* __restrict__ lwb2,
    float* __restrict__ lwI, float* __restrict__ lbI,
    float* __restrict__ lob2) {
  int i = blockIdx.x * 256 + threadIdx.x;
  if (i < 81920) {
    float w = (i < 32768) ? Wq[i] : (i < 65536) ? Wk[i - 32768] : Wv[i - 65536];
    Wall[i] = f2bf(w);
    float lw = (i < 32768) ? lwq[i] : (i < 65536) ? lwk[i - 32768] : lwv[i - 65536];
    float lb = (i < 32768) ? lbq[i] : (i < 65536) ? lbk[i - 32768] : lbv[i - 65536];
    lwb2[(size_t)i * 2] = lw;
    lwb2[(size_t)i * 2 + 1] = lb;
    int gm = i >> 7, f = i & 127;
    if (gm >= 512) {
      int hm = gm - 512;
      size_t idx = ((size_t)(hm >> 2) * 128 + f) * 4 + (hm & 3);
      lwI[idx] = lw;
      lbI[idx] = lb;
    }
  }
  if (i < 16384) {
    Wo2[i] = f2bf(Wo[i]);
    lob2[(size_t)i * 2] = lwo[i];
    lob2[(size_t)i * 2 + 1] = lbo[i];
  }
  if (i < 640) {
    ball[i] = (i < 256) ? bq[i] : (i < 512) ? bk[i - 256] : bv[i - 512];
    aall[i] = (i < 256) ? aq[i >> 6] : (i < 512) ? ak[(i - 256) >> 6] : av[(i - 512) >> 5];
  }
}

// ---------------------------------------------------------------------------
// xT[b][(t*128+f)][c] bf16  <-  x[b][c][t][f] fp32.  One block per (b,t).
__global__ __launch_bounds__(256) void xT_kernel(const float* __restrict__ x,
                                                 unsigned short* __restrict__ xT) {
  __shared__ unsigned short tile[128][136];  // [c][f]
  int bx = blockIdx.x;
  int t = bx & 511;
  int b = bx >> 9;
  int tid = threadIdx.x;
#pragma unroll
  for (int j = 0; j < 16; ++j) {
    int ch = j * 256 + tid;
    int c = ch >> 5;
    int fc = ch & 31;
    float4 v = *reinterpret_cast<const float4*>(
        x + (((size_t)b * C + c) * T + t) * F + fc * 4);
    unsigned short o[4] = {f2bf(v.x), f2bf(v.y), f2bf(v.z), f2bf(v.w)};
    *reinterpret_cast<ushort4*>(&tile[c][fc * 4]) = *reinterpret_cast<const ushort4*>(o);
  }
  __syncthreads();
  int f = tid >> 1, half = tid & 1;
  unsigned short* dst = xT + ((size_t)b * 65536 + (size_t)t * 128 + f) * 128 + half * 64;
#pragma unroll
  for (int g8 = 0; g8 < 8; ++g8) {
    unsigned short o[8];
#pragma unroll
    for (int kk = 0; kk < 8; ++kk) o[kk] = tile[half * 64 + g8 * 8 + kk][f];
    *reinterpret_cast<uint4*>(dst + g8 * 8) = *reinterpret_cast<const uint4*>(o);
  }
}

// ---------------------------------------------------------------------------
// Fused projection GEMM — R7 block structure; t-major grid order (5 m-tile
// blocks of one t are consecutive v -> same XCD -> L2-hit B staging);
// epilogue tables packed as (lw,lb) float2 pairs.
__global__ __launch_bounds__(256) void proj_gemm_kernel(
    const unsigned short* __restrict__ Wall, const unsigned short* __restrict__ xT,
    const float* __restrict__ ball, const float* __restrict__ aall,
    const float* __restrict__ lwb2,
    const float* __restrict__ lwI, const float* __restrict__ lbI,
    unsigned short* __restrict__ qf, unsigned short* __restrict__ kf,
    unsigned short* __restrict__ vf) {
  __shared__ alignas(16) unsigned short As[128 * 64];
  __shared__ alignas(16) unsigned short Bs[128 * 64];
  __shared__ float part[4][2][2];

  int p = blockIdx.x;
  int cpx = gridDim.x >> 3;  // 1280
  int v = (p & 7) * cpx + (p >> 3);
  int bb = v / 2560;
  int tl = v - bb * 2560;
  int t = tl / 5;            // t fastest-but-one: 5 m-tiles of one t adjacent
  int tm = tl - t * 5;

  int tid = threadIdx.x;
  int w = tid >> 6, lane = tid & 63;
  int wr = w >> 1, wc = w & 1;
  int lr = lane & 15, kg = lane >> 4;

  const unsigned short* Ab = Wall + (size_t)tm * 128 * 128;
  const unsigned short* Bb = xT + ((size_t)bb * 65536 + (size_t)t * 128) * 128;

  f32x4 acc[4][4] = {};
  for (int k0 = 0; k0 < 128; k0 += 64) {
#pragma unroll
    for (int j = 0; j < 4; ++j) {
      int ch = j * 256 + tid;
      int r = ch >> 3;
      int c = (ch & 7) * 8;
      gl_lds16(Ab + (size_t)r * 128 + k0 + c, &As[ch * 8]);
      gl_lds16(Bb + (size_t)r * 128 + k0 + c, &Bs[ch * 8]);
    }
    __syncthreads();
#pragma unroll
    for (int ks = 0; ks < 2; ++ks) {
      bf16x8 af[4], bfr[4];
#pragma unroll
      for (int m = 0; m < 4; ++m)
        af[m] = *reinterpret_cast<const bf16x8*>(
            &As[(wr * 64 + m * 16 + lr) * 64 + ks * 32 + kg * 8]);
#pragma unroll
      for (int n = 0; n < 4; ++n)
        bfr[n] = *reinterpret_cast<const bf16x8*>(
            &Bs[(wc * 64 + n * 16 + lr) * 64 + ks * 32 + kg * 8]);
#pragma unroll
      for (int m = 0; m < 4; ++m)
#pragma unroll
        for (int n = 0; n < 4; ++n)
          acc[m][n] = __builtin_amdgcn_mfma_f32_16x16x32_bf16(af[m], bfr[n], acc[m][n], 0, 0, 0);
    }
    __syncthreads();
  }

  int sec = (tm < 2) ? 0 : (tm < 4 ? 1 : 2);
  float s[2] = {0.f, 0.f}, s2[2] = {0.f, 0.f};
#pragma unroll
  for (int m = 0; m < 4; ++m) {
    int g = (sec == 2) ? (m >> 1) : 0;
    int gm0 = tm * 128 + wr * 64 + m * 16 + kg * 4;
    float4 bi4 = *reinterpret_cast<const float4*>(&ball[gm0]);
    float4 al4 = *reinterpret_cast<const float4*>(&aall[gm0]);
    const float bi[4] = {bi4.x, bi4.y, bi4.z, bi4.w};
    const float al[4] = {al4.x, al4.y, al4.z, al4.w};
#pragma unroll
    for (int j = 0; j < 4; ++j) {
#pragma unroll
      for (int n = 0; n < 4; ++n) {
        float val = acc[m][n][j] + bi[j];
        val = val >= 0.f ? val : al[j] * val;
        acc[m][n][j] = val;
        s[g] += val;
        s2[g] += val * val;
      }
    }
  }
#pragma unroll
  for (int off = 32; off >= 1; off >>= 1) {
    s[0] += __shfl_xor(s[0], off, 64);
    s2[0] += __shfl_xor(s2[0], off, 64);
    s[1] += __shfl_xor(s[1], off, 64);
    s2[1] += __shfl_xor(s2[1], off, 64);
  }
  if (lane == 0) {
    part[w][0][0] = s[0]; part[w][0][1] = s2[0];
    part[w][1][0] = s[1]; part[w][1][1] = s2[1];
  }
  __syncthreads();
  float invN = (sec == 2) ? (1.f / 4096.f) : (1.f / 8192.f);
  float mu[2], rs[2];
#pragma unroll
  for (int g = 0; g < 2; ++g) {
    float S = part[2 * wr][g][0] + part[2 * wr + 1][g][0];
    float S2 = part[2 * wr][g][1] + part[2 * wr + 1][g][1];
    float m_ = S * invN;
    float var = S2 * invN - m_ * m_;
    mu[g] = m_;
    rs[g] = rsqrtf(var + EPS);
  }

#pragma unroll
  for (int m = 0; m < 4; ++m) {
    int g = (sec == 2) ? (m >> 1) : 0;
    float mu_ = mu[g], rs_ = rs[g];
    int row0 = wr * 64 + m * 16 + kg * 4;
    int gm0 = tm * 128 + row0;
    if (sec < 2) {
#pragma unroll
      for (int j = 0; j < 4; ++j) {
        int gm = gm0 + j;
        const float* wbr = lwb2 + (size_t)gm * 256;  // [f][2]
        unsigned short* dst;
        if (sec == 0) {
          int h = gm >> 6, d = gm & 63;
          dst = qf + (((size_t)bb * H + h) * T + t) * E + d * 128;
        } else {
          int hm = gm - 256, h = hm >> 6, d = hm & 63;
          dst = kf + (((size_t)bb * H + h) * T + t) * E + d * 128;
        }
#pragma unroll
        for (int n = 0; n < 4; ++n) {
          int f = wc * 64 + n * 16 + lr;
          float2 p2 = *reinterpret_cast<const float2*>(wbr + f * 2);
          dst[f] = f2bf((acc[m][n][j] - mu_) * rs_ * p2.x + p2.y);
        }
      }
    } else {
      int hm = gm0 - 512;
      int h = hm >> 5, d0 = hm & 31;
      int gmg = hm >> 2;
      unsigned short* dstb = vf + (((size_t)bb * H + h) * T + t) * EV;
      const float* lw0 = lwI + (size_t)gmg * 512;
      const float* lb0 = lbI + (size_t)gmg * 512;
#pragma unroll
      for (int n = 0; n < 4; ++n) {
        int f = wc * 64 + n * 16 + lr;
        float4 w4 = *reinterpret_cast<const float4*>(lw0 + f * 4);
        float4 b4 = *reinterpret_cast<const float4*>(lb0 + f * 4);
        unsigned short o[4];
        o[0] = f2bf((acc[m][n][0] - mu_) * rs_ * w4.x + b4.x);
        o[1] = f2bf((acc[m][n][1] - mu_) * rs_ * w4.y + b4.y);
        o[2] = f2bf((acc[m][n][2] - mu_) * rs_ * w4.z + b4.z);
        o[3] = f2bf((acc[m][n][3] - mu_) * rs_ * w4.w + b4.w);
        *reinterpret_cast<ushort4*>(dstb + (size_t)f * 32 + d0) =
            *reinterpret_cast<const ushort4*>(o);
      }
    }
  }
}

// ---------------------------------------------------------------------------
// MFMA GEMM, A·B^T with K-split. OMODE: 0=f32, 1=bf16, 2=f16 output.
template <int OMODE>
__global__ __launch_bounds__(256) void gemm_bt_kernel(
    const unsigned short* __restrict__ A, const unsigned short* __restrict__ Bm,
    void* __restrict__ Out, int M, int N, int K, float scale,
    int tiles_m, int tiles_n, int kchunks, int nb) {
  __shared__ alignas(16) unsigned short As[128 * 64];
  __shared__ alignas(16) unsigned short Bs[128 * 64];

  int p = blockIdx.x;
  int cpx = gridDim.x >> 3;
  int v = (p & 7) * cpx + (p >> 3);
  int tpb = tiles_m * tiles_n;
  int per_bh = tpb * kchunks;
  int bh = v / per_bh;
  int r0 = v - bh * per_bh;
  int kc = r0 / tpb;
  int tl = r0 - kc * tpb;
  int tm = tl / tiles_n;
  int tn = tl - tm * tiles_n;

  int tid = threadIdx.x;
  int w = tid >> 6, lane = tid & 63;
  int wr = w >> 1, wc = w & 1;
  int lr = lane & 15, kg = lane >> 4;

  const unsigned short* Ab = A + ((size_t)bh * M + tm * 128) * K;
  const unsigned short* Bb = Bm + ((size_t)bh * N + tn * 128) * K;

  int klen = K / kchunks;
  int kb = kc * klen;

  f32x4 acc[4][4] = {};
  for (int k0 = kb; k0 < kb + klen; k0 += 64) {
#pragma unroll
    for (int j = 0; j < 4; ++j) {
      int ch = j * 256 + tid;
      int r = ch >> 3;
      int c = (ch & 7) * 8;
      gl_lds16(Ab + (size_t)r * K + k0 + c, &As[ch * 8]);
      gl_lds16(Bb + (size_t)r * K + k0 + c, &Bs[ch * 8]);
    }
    __syncthreads();
#pragma unroll
    for (int ks = 0; ks < 2; ++ks) {
      bf16x8 af[4], bf[4];
#pragma unroll
      for (int m = 0; m < 4; ++m)
        af[m] = *reinterpret_cast<const bf16x8*>(
            &As[(wr * 64 + m * 16 + lr) * 64 + ks * 32 + kg * 8]);
#pragma unroll
      for (int n = 0; n < 4; ++n)
        bf[n] = *reinterpret_cast<const bf16x8*>(
            &Bs[(wc * 64 + n * 16 + lr) * 64 + ks * 32 + kg * 8]);
#pragma unroll
      for (int m = 0; m < 4; ++m)
#pragma unroll
        for (int n = 0; n < 4; ++n)
          acc[m][n] = __builtin_amdgcn_mfma_f32_16x16x32_bf16(af[m], bf[n], acc[m][n], 0, 0, 0);
    }
    __syncthreads();
  }

  int orow = tm * 128 + wr * 64 + kg * 4;
  int ocol = tn * 128 + wc * 64 + lr;
  size_t obase = (size_t)(kc * nb + bh) * M * N;
  if constexpr (OMODE == 1) {
    unsigned short* O = (unsigned short*)Out + obase;
#pragma unroll
    for (int m = 0; m < 4; ++m)
#pragma unroll
      for (int j = 0; j < 4; ++j) {
        size_t base = (size_t)(orow + m * 16 + j) * N + ocol;
#pragma unroll
        for (int n = 0; n < 4; ++n)
          O[base + n * 16] = f2bf(acc[m][n][j] * scale);
      }
  } else if constexpr (OMODE == 2) {
    unsigned short* O = (unsigned short*)Out + obase;
#pragma unroll
    for (int m = 0; m < 4; ++m)
#pragma unroll
      for (int j = 0; j < 4; ++j) {
        size_t base = (size_t)(orow + m * 16 + j) * N + ocol;
#pragma unroll
        for (int n = 0; n < 4; ++n)
          O[base + n * 16] = f2h(acc[m][n][j] * scale);
      }
  } else {
    float* O = (float*)Out + obase;
#pragma unroll
    for (int m = 0; m < 4; ++m)
#pragma unroll
      for (int j = 0; j < 4; ++j) {
        size_t base = (size_t)(orow + m * 16 + j) * N + ocol;
#pragma unroll
        for (int n = 0; n < 4; ++n)
          O[base + n * 16] = acc[m][n][j] * scale;
      }
  }
}

// ---------------------------------------------------------------------------
// Transpose vf [bh][T][EV] -> vfT [bh][EV][T] (bf16), 64x64 tiles
__global__ __launch_bounds__(256) void transpose_v_kernel(
    const unsigned short* __restrict__ src, unsigned short* __restrict__ dst) {
  __shared__ unsigned short tile[64][72];
  int bx = blockIdx.x;
  int et = bx & 63;
  int tt = (bx >> 6) & 7;
  int bh = bx >> 9;
  const unsigned short* sb = src + ((size_t)bh * T + tt * 64) * EV + et * 64;
#pragma unroll
  for (int j = 0; j < 2; ++j) {
    int ch = j * 256 + threadIdx.x;
    int r = ch >> 3;
    int c8 = ch & 7;
    uint4 u = *reinterpret_cast<const uint4*>(sb + (size_t)r * EV + c8 * 8);
    *reinterpret_cast<uint4*>(&tile[r][c8 * 8]) = u;
  }
  __syncthreads();
  unsigned short* db = dst + ((size_t)bh * EV + et * 64) * T + tt * 64;
#pragma unroll
  for (int j = 0; j < 2; ++j) {
    int ch = j * 256 + threadIdx.x;
    int r = ch >> 3;
    int c8 = ch & 7;
    unsigned short o[8];
#pragma unroll
    for (int i = 0; i < 8; ++i) o[i] = tile[c8 * 8 + i][r];
    *reinterpret_cast<uint4*>(db + (size_t)r * T + c8 * 8) =
        *reinterpret_cast<const uint4*>(o);
  }
}

// ---------------------------------------------------------------------------
// Softmax over last dim (512); sums nchunk fp16 partials -> bf16 probs
__global__ __launch_bounds__(64) void softmax_kernel(const unsigned short* __restrict__ a,
                                                     unsigned short* __restrict__ ob,
                                                     int nchunk) {
  const size_t cs = (size_t)8192 * 512;
  const unsigned short* pr = a + (size_t)blockIdx.x * T;
  int tid = threadIdx.x;
  float v[8];
  uint4 u = *reinterpret_cast<const uint4*>(pr + tid * 8);
  const unsigned short* up = reinterpret_cast<const unsigned short*>(&u);
#pragma unroll
  for (int i = 0; i < 8; ++i) v[i] = h2f(up[i]);
  for (int c = 1; c < nchunk; ++c) {
    uint4 u2 = *reinterpret_cast<const uint4*>(pr + c * cs + tid * 8);
    const unsigned short* u2p = reinterpret_cast<const unsigned short*>(&u2);
#pragma unroll
    for (int i = 0; i < 8; ++i) v[i] += h2f(u2p[i]);
  }
  float mx = v[0];
#pragma unroll
  for (int i = 1; i < 8; ++i) mx = fmaxf(mx, v[i]);
#pragma unroll
  for (int off = 32; off >= 1; off >>= 1) mx = fmaxf(mx, __shfl_xor(mx, off, 64));
  float sm = 0.f;
#pragma unroll
  for (int i = 0; i < 8; ++i) { v[i] = __expf(v[i] - mx); sm += v[i]; }
#pragma unroll
  for (int off = 32; off >= 1; off >>= 1) sm += __shfl_xor(sm, off, 64);
  float r = 1.0f / sm;
  unsigned short o[8];
#pragma unroll
  for (int i = 0; i < 8; ++i) o[i] = f2bf(v[i] * r);
  *reinterpret_cast<uint4*>(ob + (size_t)blockIdx.x * T + tid * 8) =
      *reinterpret_cast<const uint4*>(o);
}

// ---------------------------------------------------------------------------
// Fused out-projection: Z = Wo2 · r^T per (b,t) + bias + PReLU + LN(C,F)
// + affine + residual(from bf16 xT) -> fp32. B staged from pv (f-major).
// Residual staged into dead As/Bs LDS with chunk-XOR swizzle.
__global__ __launch_bounds__(256) void outproj_gemm_kernel(
    const unsigned short* __restrict__ Wo2, const unsigned short* __restrict__ pv,
    const unsigned short* __restrict__ xT,
    const float* __restrict__ bo, const float* __restrict__ ao,
    const float* __restrict__ lob2, float* __restrict__ outp) {
  __shared__ alignas(16) unsigned short Sm[2 * 128 * 64];  // As|Bs, reused as Rs
  unsigned short* As = Sm;
  unsigned short* Bs = Sm + 128 * 64;
  unsigned short* Rs = Sm;  // 128 x 128 bf16 residual, chunk-swizzled
  __shared__ float part[4][2];

  int p = blockIdx.x;
  int cpx = gridDim.x >> 3;
  int v = (p & 7) * cpx + (p >> 3);
  int bb = v >> 9;
  int t = v & 511;

  int tid = threadIdx.x;
  int w = tid >> 6, lane = tid & 63;
  int wr = w >> 1, wc = w & 1;
  int lr = lane & 15, kg = lane >> 4;

  const unsigned short* pvb = pv + (size_t)bb * H * T * EV + (size_t)t * EV;

  f32x4 acc[4][4] = {};
  for (int k0 = 0; k0 < 128; k0 += 64) {
#pragma unroll
    for (int j = 0; j < 4; ++j) {
      int ch = j * 256 + tid;
      int r = ch >> 3;
      int c0 = (ch & 7) * 8;
      gl_lds16(Wo2 + (size_t)r * 128 + k0 + c0, &As[ch * 8]);
      int cc = k0 + c0;
      int h = cc >> 5, dv0 = cc & 31;
      gl_lds16(pvb + (size_t)h * T * EV + (size_t)r * 32 + dv0, &Bs[ch * 8]);
    }
    __syncthreads();
#pragma unroll
    for (int ks = 0; ks < 2; ++ks) {
      bf16x8 af[4], bf[4];
#pragma unroll
      for (int m = 0; m < 4; ++m)
        af[m] = *reinterpret_cast<const bf16x8*>(
            &As[(wr * 64 + m * 16 + lr) * 64 + ks * 32 + kg * 8]);
#pragma unroll
      for (int n = 0; n < 4; ++n)
        bf[n] = *reinterpret_cast<const bf16x8*>(
            &Bs[(wc * 64 + n * 16 + lr) * 64 + ks * 32 + kg * 8]);
#pragma unroll
      for (int m = 0; m < 4; ++m)
#pragma unroll
        for (int n = 0; n < 4; ++n)
          acc[m][n] = __builtin_amdgcn_mfma_f32_16x16x32_bf16(af[m], bf[n], acc[m][n], 0, 0, 0);
    }
    __syncthreads();
  }

  // Stage residual: xT slab row f. LDS slot s of row f holds global chunk
  // s^(f&15) (pre-swizzled source, linear dest -- rule #21).
  const unsigned short* xTb = xT + ((size_t)bb * 65536 + (size_t)t * 128) * 128;
#pragma unroll
  for (int j = 0; j < 8; ++j) {
    int ch = j * 256 + tid;
    int f = ch >> 4;
    int s = ch & 15;
    gl_lds16(xTb + (size_t)f * 128 + ((s ^ (f & 15)) * 8), &Rs[ch * 8]);
  }

  float aO = ao[0];
  float s = 0.f, s2 = 0.f;
#pragma unroll
  for (int m = 0; m < 4; ++m)
#pragma unroll
    for (int j = 0; j < 4; ++j) {
      int d = wr * 64 + m * 16 + kg * 4 + j;
      float bi = bo[d];
#pragma unroll
      for (int n = 0; n < 4; ++n) {
        float val = acc[m][n][j] + bi;
        val = val >= 0.f ? val : aO * val;
        acc[m][n][j] = val;
        s += val;
        s2 += val * val;
      }
    }
#pragma unroll
  for (int off = 32; off >= 1; off >>= 1) {
    s += __shfl_xor(s, off, 64);
    s2 += __shfl_xor(s2, off, 64);
  }
  if (lane == 0) { part[w][0] = s; part[w][1] = s2; }
  __syncthreads();  // part visible + vmcnt drained -> Rs ready
  float S = part[0][0] + part[1][0] + part[2][0] + part[3][0];
  float S2 = part[0][1] + part[1][1] + part[2][1] + part[3][1];
  const float invN = 1.f / 16384.f;
  float mu = S * invN;
  float var = S2 * invN - mu * mu;
  float rstd = rsqrtf(var + EPS);
#pragma unroll
  for (int m = 0; m < 4; ++m) {
    int d0 = wr * 64 + m * 16 + kg * 4;
#pragma unroll
    for (int n = 0; n < 4; ++n) {
      int f = wc * 64 + n * 16 + lr;
      int ra = f * 128 + (((d0 >> 3) ^ (f & 15)) << 3) + (d0 & 7);
      ushort4 rv = *reinterpret_cast<const ushort4*>(&Rs[ra]);
      const unsigned short* rp = reinterpret_cast<const unsigned short*>(&rv);
#pragma unroll
      for (int j = 0; j < 4; ++j) {
        int d = d0 + j;
        float2 p2 = *reinterpret_cast<const float2*>(lob2 + ((size_t)d * 128 + f) * 2);
        float val = (acc[m][n][j] - mu) * rstd * p2.x + p2.y;
        size_t xi = (((size_t)bb * C + d) * T + t) * F + f;
        outp[xi] = val + bf2f(rp[j]);
      }
    }
  }
}

// ---------------------------------------------------------------------------
extern "C" void kernel_launch(void* const* d_in, const int* in_sizes, int n_in,
                              void* d_out, int out_size, void* d_ws, size_t ws_size,
                              hipStream_t stream) {
  const float* x   = (const float*)d_in[0];
  const float* Wq  = (const float*)d_in[1];
  const float* bq  = (const float*)d_in[2];
  const float* aq  = (const float*)d_in[3];
  const float* lwq = (const float*)d_in[4];
  const float* lbq = (const float*)d_in[5];
  const float* Wk  = (const float*)d_in[6];
  const float* bk_ = (const float*)d_in[7];
  const float* ak  = (const float*)d_in[8];
  const float* lwk = (const float*)d_in[9];
  const float* lbk = (const float*)d_in[10];
  const float* Wv  = (const float*)d_in[11];
  const float* bv  = (const float*)d_in[12];
  const float* av  = (const float*)d_in[13];
  const float* lwv = (const float*)d_in[14];
  const float* lbv = (const float*)d_in[15];
  const float* Wo  = (const float*)d_in[16];
  const float* bo  = (const float*)d_in[17];
  const float* ao  = (const float*)d_in[18];
  const float* lwo = (const float*)d_in[19];
  const float* lbo = (const float*)d_in[20];
  float* outp = (float*)d_out;

  char* ws = (char*)d_ws;
  // phase-1: qf 0..128M, kf 128..256M, vf 256..320M, xT 320..384M (ALIVE to end)
  unsigned short* qfp = (unsigned short*)(ws);
  unsigned short* kfp = (unsigned short*)(ws + 134217728ull);
  unsigned short* vfp = (unsigned short*)(ws + 268435456ull);
  unsigned short* xT  = (unsigned short*)(ws + 335544320ull);
  // tail tables @ 402653184: long-lived first (Wo2, lob2), then proj-dead.
  unsigned short* Wo2   = (unsigned short*)(ws + 402653184ull);  // 32 KB (till outproj)
  float*          lob2  = (float*)(ws + 402685952ull);           // 128 KB (till outproj)
  float*          ball  = (float*)(ws + 402817024ull);           // 4 KB  (dead after proj)
  float*          aall  = (float*)(ws + 402821120ull);           // 4 KB
  float*          lwI   = (float*)(ws + 402825216ull);           // 64 KB
  float*          lbI   = (float*)(ws + 402890752ull);           // 64 KB
  unsigned short* Wall  = (unsigned short*)(ws + 402956288ull);  // 160 KB
  float*          lwb2  = (float*)(ws + 403120128ull);           // 640 KB -> 403775488
  // atnP fp16 (kchunks=2, 16.8 MB) overlays proj-dead region from ball onward:
  // 402817024 + 16777216 = 419594240 <= proven 419823616 footprint.
  unsigned short* atnP = (unsigned short*)(ws + 402817024ull);
  // phase-2 reuse
  unsigned short* atnb = (unsigned short*)(ws);                  //  8 MB (ex-qf)
  unsigned short* vfT  = (unsigned short*)(ws + 134217728ull);   // 64 MB (ex-kf)
  unsigned short* pvp  = (unsigned short*)(ws + 268435456ull);   // 64 MB (ex-vf)

  prep_kernel<<<320, 256, 0, stream>>>(Wq, Wk, Wv, Wo, bq, bk_, bv, aq, ak, av,
                                       lwq, lwk, lwv, lbq, lbk, lbv, lwo, lbo,
                                       Wall, Wo2, ball, aall, lwb2, lwI, lbI, lob2);

  xT_kernel<<<2048, 256, 0, stream>>>(x, xT);

  // R7-proven projection, t-major grid order + packed tables
  proj_gemm_kernel<<<10240, 256, 0, stream>>>(Wall, xT, ball, aall,
                                              lwb2, lwI, lbI,
                                              qfp, kfp, vfp);

  // logits K-split x2, fp16 partials into atnP[kc][bh][512][512]
  gemm_bt_kernel<2><<<512, 256, 0, stream>>>(
      qfp, kfp, atnP, 512, 512, 8192, 0.011048543456039806f, 4, 4, 2, 16);

  // vf -> vfT (into ex-kf; kf dead after logits)
  transpose_v_kernel<<<8192, 256, 0, stream>>>(vfp, vfT);

  // softmax: sum 2 fp16 partials -> bf16 probs (into ex-qf)
  softmax_kernel<<<8192, 64, 0, stream>>>(atnP, atnb, 2);

  // PV: O = P V  (M=512, N=4096, K=512), bf16 out; e' = f*32+dv layout
  gemm_bt_kernel<1><<<2048, 256, 0, stream>>>(
      atnb, vfT, pvp, 512, 4096, 512, 1.0f, 4, 32, 1, 16);

  // out-projection: B from pv, residual from bf16 xT
  outproj_gemm_kernel<<<2048, 256, 0, stream>>>(Wo2, pvp, xT, bo, ao, lob2, outp);
}

// Round 12
// 500.551 us; speedup vs baseline: 1.0787x; 1.0787x over previous
//
#include <hip/hip_runtime.h>
#include <hip/hip_bf16.h>
#include <hip/hip_fp16.h>

// Problem constants
constexpr int B = 4, C = 128, T = 512, F = 128, H = 4, D = 64, DV = 32;
constexpr int E  = D * F;   // 8192
constexpr int EV = DV * F;  // 4096
constexpr float EPS = 1e-5f;

// Layouts: qf/kf d-major [b][h][t][d*128+f]; vf/pv f-major [b][h][t][f*32+dv].
// attn logit partials stored fp16 (kchunks=2). Residual read from bf16 xT.

typedef __attribute__((ext_vector_type(4))) float f32x4;
typedef __attribute__((ext_vector_type(8))) short bf16x8;

__device__ __forceinline__ float bf2f(unsigned short u) {
  return __uint_as_float(((unsigned int)u) << 16);
}
__device__ __forceinline__ unsigned short f2bf(float f) {
  unsigned int b = __float_as_uint(f);
  unsigned int r = b + 0x7FFFu + ((b >> 16) & 1u);
  return (unsigned short)(r >> 16);
}
__device__ __forceinline__ unsigned short f2h(float f) {
  __half h = __float2half(f);
  return __half_as_ushort(h);
}
__device__ __forceinline__ float h2f(unsigned short u) {
  return __half2float(__ushort_as_half(u));
}

__device__ __forceinline__ void gl_lds16(const unsigned short* g, unsigned short* l) {
  __builtin_amdgcn_global_load_lds(
      (const __attribute__((address_space(1))) unsigned int*)(g),
      (__attribute__((address_space(3))) unsigned int*)(l), 16, 0, 0);
}

// ---------------------------------------------------------------------------
// Pack weights (R7 form)
__global__ __launch_bounds__(256) void prep_kernel(
    const float* __restrict__ Wq, const float* __restrict__ Wk,
    const float* __restrict__ Wv, const float* __restrict__ Wo,
    const float* __restrict__ bq, const float* __restrict__ bk,
    const float* __restrict__ bv, const float* __restrict__ aq,
    const float* __restrict__ ak, const float* __restrict__ av,
    const float* __restrict__ lwq, const float* __restrict__ lwk,
    const float* __restrict__ lwv, const float* __restrict__ lbq,
    const float* __restrict__ lbk, const float* __restrict__ lbv,
    unsigned short* __restrict__ Wall, unsigned short* __restrict__ Wo2,
    float* __restrict__ ball, float* __restrict__ aall,
    float* __restrict__ lwall, float* __restrict__ lball,
    float* __restrict__ lwI, float* __restrict__ lbI) {
  int i = blockIdx.x * 256 + threadIdx.x;
  if (i < 81920) {
    float w = (i < 32768) ? Wq[i] : (i < 65536) ? Wk[i - 32768] : Wv[i - 65536];
    Wall[i] = f2bf(w);
    float lw = (i < 32768) ? lwq[i] : (i < 65536) ? lwk[i - 32768] : lwv[i - 65536];
    float lb = (i < 32768) ? lbq[i] : (i < 65536) ? lbk[i - 32768] : lbv[i - 65536];
    lwall[i] = lw;
    lball[i] = lb;
    int gm = i >> 7, f = i & 127;
    if (gm >= 512) {
      int hm = gm - 512;
      size_t idx = ((size_t)(hm >> 2) * 128 + f) * 4 + (hm & 3);
      lwI[idx] = lw;
      lbI[idx] = lb;
    }
  }
  if (i < 16384) Wo2[i] = f2bf(Wo[i]);
  if (i < 640) {
    ball[i] = (i < 256) ? bq[i] : (i < 512) ? bk[i - 256] : bv[i - 512];
    aall[i] = (i < 256) ? aq[i >> 6] : (i < 512) ? ak[(i - 256) >> 6] : av[(i - 512) >> 5];
  }
}

// ---------------------------------------------------------------------------
// xT[b][(t*128+f)][c] bf16  <-  x[b][c][t][f] fp32.  One block per (b,t).
__global__ __launch_bounds__(256) void xT_kernel(const float* __restrict__ x,
                                                 unsigned short* __restrict__ xT) {
  __shared__ unsigned short tile[128][136];  // [c][f]
  int bx = blockIdx.x;
  int t = bx & 511;
  int b = bx >> 9;
  int tid = threadIdx.x;
#pragma unroll
  for (int j = 0; j < 16; ++j) {
    int ch = j * 256 + tid;
    int c = ch >> 5;
    int fc = ch & 31;
    float4 v = *reinterpret_cast<const float4*>(
        x + (((size_t)b * C + c) * T + t) * F + fc * 4);
    unsigned short o[4] = {f2bf(v.x), f2bf(v.y), f2bf(v.z), f2bf(v.w)};
    *reinterpret_cast<ushort4*>(&tile[c][fc * 4]) = *reinterpret_cast<const ushort4*>(o);
  }
  __syncthreads();
  int f = tid >> 1, half = tid & 1;
  unsigned short* dst = xT + ((size_t)b * 65536 + (size_t)t * 128 + f) * 128 + half * 64;
#pragma unroll
  for (int g8 = 0; g8 < 8; ++g8) {
    unsigned short o[8];
#pragma unroll
    for (int kk = 0; kk < 8; ++kk) o[kk] = tile[half * 64 + g8 * 8 + kk][f];
    *reinterpret_cast<uint4*>(dst + g8 * 8) = *reinterpret_cast<const uint4*>(o);
  }
}

// ---------------------------------------------------------------------------
// Fused projection GEMM — EXACT R7 version (measured 190 us).
__global__ __launch_bounds__(256) void proj_gemm_kernel(
    const unsigned short* __restrict__ Wall, const unsigned short* __restrict__ xT,
    const float* __restrict__ ball, const float* __restrict__ aall,
    const float* __restrict__ lwall, const float* __restrict__ lball,
    const float* __restrict__ lwI, const float* __restrict__ lbI,
    unsigned short* __restrict__ qf, unsigned short* __restrict__ kf,
    unsigned short* __restrict__ vf) {
  __shared__ alignas(16) unsigned short As[128 * 64];
  __shared__ alignas(16) unsigned short Bs[128 * 64];
  __shared__ float part[4][2][2];

  int p = blockIdx.x;
  int cpx = gridDim.x >> 3;
  int v = (p & 7) * cpx + (p >> 3);
  int bb = v / 2560;
  int tl = v - bb * 2560;
  int tm = tl / 512;
  int t = tl - tm * 512;

  int tid = threadIdx.x;
  int w = tid >> 6, lane = tid & 63;
  int wr = w >> 1, wc = w & 1;
  int lr = lane & 15, kg = lane >> 4;

  const unsigned short* Ab = Wall + (size_t)tm * 128 * 128;
  const unsigned short* Bb = xT + ((size_t)bb * 65536 + (size_t)t * 128) * 128;

  f32x4 acc[4][4] = {};
  for (int k0 = 0; k0 < 128; k0 += 64) {
#pragma unroll
    for (int j = 0; j < 4; ++j) {
      int ch = j * 256 + tid;
      int r = ch >> 3;
      int c = (ch & 7) * 8;
      gl_lds16(Ab + (size_t)r * 128 + k0 + c, &As[ch * 8]);
      gl_lds16(Bb + (size_t)r * 128 + k0 + c, &Bs[ch * 8]);
    }
    __syncthreads();
#pragma unroll
    for (int ks = 0; ks < 2; ++ks) {
      bf16x8 af[4], bfr[4];
#pragma unroll
      for (int m = 0; m < 4; ++m)
        af[m] = *reinterpret_cast<const bf16x8*>(
            &As[(wr * 64 + m * 16 + lr) * 64 + ks * 32 + kg * 8]);
#pragma unroll
      for (int n = 0; n < 4; ++n)
        bfr[n] = *reinterpret_cast<const bf16x8*>(
            &Bs[(wc * 64 + n * 16 + lr) * 64 + ks * 32 + kg * 8]);
#pragma unroll
      for (int m = 0; m < 4; ++m)
#pragma unroll
        for (int n = 0; n < 4; ++n)
          acc[m][n] = __builtin_amdgcn_mfma_f32_16x16x32_bf16(af[m], bfr[n], acc[m][n], 0, 0, 0);
    }
    __syncthreads();
  }

  int sec = (tm < 2) ? 0 : (tm < 4 ? 1 : 2);
  float s[2] = {0.f, 0.f}, s2[2] = {0.f, 0.f};
#pragma unroll
  for (int m = 0; m < 4; ++m) {
    int g = (sec == 2) ? (m >> 1) : 0;
    int gm0 = tm * 128 + wr * 64 + m * 16 + kg * 4;
    float4 bi4 = *reinterpret_cast<const float4*>(&ball[gm0]);
    float4 al4 = *reinterpret_cast<const float4*>(&aall[gm0]);
    const float bi[4] = {bi4.x, bi4.y, bi4.z, bi4.w};
    const float al[4] = {al4.x, al4.y, al4.z, al4.w};
#pragma unroll
    for (int j = 0; j < 4; ++j) {
#pragma unroll
      for (int n = 0; n < 4; ++n) {
        float val = acc[m][n][j] + bi[j];
        val = val >= 0.f ? val : al[j] * val;
        acc[m][n][j] = val;
        s[g] += val;
        s2[g] += val * val;
      }
    }
  }
#pragma unroll
  for (int off = 32; off >= 1; off >>= 1) {
    s[0] += __shfl_xor(s[0], off, 64);
    s2[0] += __shfl_xor(s2[0], off, 64);
    s[1] += __shfl_xor(s[1], off, 64);
    s2[1] += __shfl_xor(s2[1], off, 64);
  }
  if (lane == 0) {
    part[w][0][0] = s[0]; part[w][0][1] = s2[0];
    part[w][1][0] = s[1]; part[w][1][1] = s2[1];
  }
  __syncthreads();
  float invN = (sec == 2) ? (1.f / 4096.f) : (1.f / 8192.f);
  float mu[2], rs[2];
#pragma unroll
  for (int g = 0; g < 2; ++g) {
    float S = part[2 * wr][g][0] + part[2 * wr + 1][g][0];
    float S2 = part[2 * wr][g][1] + part[2 * wr + 1][g][1];
    float m_ = S * invN;
    float var = S2 * invN - m_ * m_;
    mu[g] = m_;
    rs[g] = rsqrtf(var + EPS);
  }

#pragma unroll
  for (int m = 0; m < 4; ++m) {
    int g = (sec == 2) ? (m >> 1) : 0;
    float mu_ = mu[g], rs_ = rs[g];
    int row0 = wr * 64 + m * 16 + kg * 4;
    int gm0 = tm * 128 + row0;
    if (sec < 2) {
#pragma unroll
      for (int j = 0; j < 4; ++j) {
        int gm = gm0 + j;
        const float* lwr = lwall + (size_t)gm * 128;
        const float* lbr = lball + (size_t)gm * 128;
        unsigned short* dst;
        if (sec == 0) {
          int h = gm >> 6, d = gm & 63;
          dst = qf + (((size_t)bb * H + h) * T + t) * E + d * 128;
        } else {
          int hm = gm - 256, h = hm >> 6, d = hm & 63;
          dst = kf + (((size_t)bb * H + h) * T + t) * E + d * 128;
        }
#pragma unroll
        for (int n = 0; n < 4; ++n) {
          int f = wc * 64 + n * 16 + lr;
          dst[f] = f2bf((acc[m][n][j] - mu_) * rs_ * lwr[f] + lbr[f]);
        }
      }
    } else {
      int hm = gm0 - 512;
      int h = hm >> 5, d0 = hm & 31;
      int gmg = hm >> 2;
      unsigned short* dstb = vf + (((size_t)bb * H + h) * T + t) * EV;
      const float* lw0 = lwI + (size_t)gmg * 512;
      const float* lb0 = lbI + (size_t)gmg * 512;
#pragma unroll
      for (int n = 0; n < 4; ++n) {
        int f = wc * 64 + n * 16 + lr;
        float4 w4 = *reinterpret_cast<const float4*>(lw0 + f * 4);
        float4 b4 = *reinterpret_cast<const float4*>(lb0 + f * 4);
        unsigned short o[4];
        o[0] = f2bf((acc[m][n][0] - mu_) * rs_ * w4.x + b4.x);
        o[1] = f2bf((acc[m][n][1] - mu_) * rs_ * w4.y + b4.y);
        o[2] = f2bf((acc[m][n][2] - mu_) * rs_ * w4.z + b4.z);
        o[3] = f2bf((acc[m][n][3] - mu_) * rs_ * w4.w + b4.w);
        *reinterpret_cast<ushort4*>(dstb + (size_t)f * 32 + d0) =
            *reinterpret_cast<const ushort4*>(o);
      }
    }
  }
}

// ---------------------------------------------------------------------------
// MFMA GEMM, A·B^T with K-split. OMODE: 0=f32, 1=bf16, 2=f16 output.
template <int OMODE>
__global__ __launch_bounds__(256) void gemm_bt_kernel(
    const unsigned short* __restrict__ A, const unsigned short* __restrict__ Bm,
    void* __restrict__ Out, int M, int N, int K, float scale,
    int tiles_m, int tiles_n, int kchunks, int nb) {
  __shared__ alignas(16) unsigned short As[128 * 64];
  __shared__ alignas(16) unsigned short Bs[128 * 64];

  int p = blockIdx.x;
  int cpx = gridDim.x >> 3;
  int v = (p & 7) * cpx + (p >> 3);
  int tpb = tiles_m * tiles_n;
  int per_bh = tpb * kchunks;
  int bh = v / per_bh;
  int r0 = v - bh * per_bh;
  int kc = r0 / tpb;
  int tl = r0 - kc * tpb;
  int tm = tl / tiles_n;
  int tn = tl - tm * tiles_n;

  int tid = threadIdx.x;
  int w = tid >> 6, lane = tid & 63;
  int wr = w >> 1, wc = w & 1;
  int lr = lane & 15, kg = lane >> 4;

  const unsigned short* Ab = A + ((size_t)bh * M + tm * 128) * K;
  const unsigned short* Bb = Bm + ((size_t)bh * N + tn * 128) * K;

  int klen = K / kchunks;
  int kb = kc * klen;

  f32x4 acc[4][4] = {};
  for (int k0 = kb; k0 < kb + klen; k0 += 64) {
#pragma unroll
    for (int j = 0; j < 4; ++j) {
      int ch = j * 256 + tid;
      int r = ch >> 3;
      int c = (ch & 7) * 8;
      gl_lds16(Ab + (size_t)r * K + k0 + c, &As[ch * 8]);
      gl_lds16(Bb + (size_t)r * K + k0 + c, &Bs[ch * 8]);
    }
    __syncthreads();
#pragma unroll
    for (int ks = 0; ks < 2; ++ks) {
      bf16x8 af[4], bf[4];
#pragma unroll
      for (int m = 0; m < 4; ++m)
        af[m] = *reinterpret_cast<const bf16x8*>(
            &As[(wr * 64 + m * 16 + lr) * 64 + ks * 32 + kg * 8]);
#pragma unroll
      for (int n = 0; n < 4; ++n)
        bf[n] = *reinterpret_cast<const bf16x8*>(
            &Bs[(wc * 64 + n * 16 + lr) * 64 + ks * 32 + kg * 8]);
#pragma unroll
      for (int m = 0; m < 4; ++m)
#pragma unroll
        for (int n = 0; n < 4; ++n)
          acc[m][n] = __builtin_amdgcn_mfma_f32_16x16x32_bf16(af[m], bf[n], acc[m][n], 0, 0, 0);
    }
    __syncthreads();
  }

  int orow = tm * 128 + wr * 64 + kg * 4;
  int ocol = tn * 128 + wc * 64 + lr;
  size_t obase = (size_t)(kc * nb + bh) * M * N;
  if constexpr (OMODE == 1) {
    unsigned short* O = (unsigned short*)Out + obase;
#pragma unroll
    for (int m = 0; m < 4; ++m)
#pragma unroll
      for (int j = 0; j < 4; ++j) {
        size_t base = (size_t)(orow + m * 16 + j) * N + ocol;
#pragma unroll
        for (int n = 0; n < 4; ++n)
          O[base + n * 16] = f2bf(acc[m][n][j] * scale);
      }
  } else if constexpr (OMODE == 2) {
    unsigned short* O = (unsigned short*)Out + obase;
#pragma unroll
    for (int m = 0; m < 4; ++m)
#pragma unroll
      for (int j = 0; j < 4; ++j) {
        size_t base = (size_t)(orow + m * 16 + j) * N + ocol;
#pragma unroll
        for (int n = 0; n < 4; ++n)
          O[base + n * 16] = f2h(acc[m][n][j] * scale);
      }
  } else {
    float* O = (float*)Out + obase;
#pragma unroll
    for (int m = 0; m < 4; ++m)
#pragma unroll
      for (int j = 0; j < 4; ++j) {
        size_t base = (size_t)(orow + m * 16 + j) * N + ocol;
#pragma unroll
        for (int n = 0; n < 4; ++n)
          O[base + n * 16] = acc[m][n][j] * scale;
      }
  }
}

// ---------------------------------------------------------------------------
// Transpose vf [bh][T][EV] -> vfT [bh][EV][T] (bf16), 64x64 tiles
__global__ __launch_bounds__(256) void transpose_v_kernel(
    const unsigned short* __restrict__ src, unsigned short* __restrict__ dst) {
  __shared__ unsigned short tile[64][72];
  int bx = blockIdx.x;
  int et = bx & 63;
  int tt = (bx >> 6) & 7;
  int bh = bx >> 9;
  const unsigned short* sb = src + ((size_t)bh * T + tt * 64) * EV + et * 64;
#pragma unroll
  for (int j = 0; j < 2; ++j) {
    int ch = j * 256 + threadIdx.x;
    int r = ch >> 3;
    int c8 = ch & 7;
    uint4 u = *reinterpret_cast<const uint4*>(sb + (size_t)r * EV + c8 * 8);
    *reinterpret_cast<uint4*>(&tile[r][c8 * 8]) = u;
  }
  __syncthreads();
  unsigned short* db = dst + ((size_t)bh * EV + et * 64) * T + tt * 64;
#pragma unroll
  for (int j = 0; j < 2; ++j) {
    int ch = j * 256 + threadIdx.x;
    int r = ch >> 3;
    int c8 = ch & 7;
    unsigned short o[8];
#pragma unroll
    for (int i = 0; i < 8; ++i) o[i] = tile[c8 * 8 + i][r];
    *reinterpret_cast<uint4*>(db + (size_t)r * T + c8 * 8) =
        *reinterpret_cast<const uint4*>(o);
  }
}

// ---------------------------------------------------------------------------
// Softmax over last dim (512); sums nchunk fp16 partials -> bf16 probs
__global__ __launch_bounds__(64) void softmax_kernel(const unsigned short* __restrict__ a,
                                                     unsigned short* __restrict__ ob,
                                                     int nchunk) {
  const size_t cs = (size_t)8192 * 512;
  const unsigned short* pr = a + (size_t)blockIdx.x * T;
  int tid = threadIdx.x;
  float v[8];
  uint4 u = *reinterpret_cast<const uint4*>(pr + tid * 8);
  const unsigned short* up = reinterpret_cast<const unsigned short*>(&u);
#pragma unroll
  for (int i = 0; i < 8; ++i) v[i] = h2f(up[i]);
  for (int c = 1; c < nchunk; ++c) {
    uint4 u2 = *reinterpret_cast<const uint4*>(pr + c * cs + tid * 8);
    const unsigned short* u2p = reinterpret_cast<const unsigned short*>(&u2);
#pragma unroll
    for (int i = 0; i < 8; ++i) v[i] += h2f(u2p[i]);
  }
  float mx = v[0];
#pragma unroll
  for (int i = 1; i < 8; ++i) mx = fmaxf(mx, v[i]);
#pragma unroll
  for (int off = 32; off >= 1; off >>= 1) mx = fmaxf(mx, __shfl_xor(mx, off, 64));
  float sm = 0.f;
#pragma unroll
  for (int i = 0; i < 8; ++i) { v[i] = __expf(v[i] - mx); sm += v[i]; }
#pragma unroll
  for (int off = 32; off >= 1; off >>= 1) sm += __shfl_xor(sm, off, 64);
  float r = 1.0f / sm;
  unsigned short o[8];
#pragma unroll
  for (int i = 0; i < 8; ++i) o[i] = f2bf(v[i] * r);
  *reinterpret_cast<uint4*>(ob + (size_t)blockIdx.x * T + tid * 8) =
      *reinterpret_cast<const uint4*>(o);
}

// ---------------------------------------------------------------------------
// Fused out-projection: Z = Wo2 · r^T per (b,t) + bias + PReLU + LN(C,F)
// + affine + residual(from bf16 xT) -> fp32. B-tile staged from pv (f-major).
// Residual staged into dead As/Bs LDS with chunk-XOR swizzle (conflict-free).
__global__ __launch_bounds__(256) void outproj_gemm_kernel(
    const unsigned short* __restrict__ Wo2, const unsigned short* __restrict__ pv,
    const unsigned short* __restrict__ xT,
    const float* __restrict__ bo, const float* __restrict__ ao,
    const float* __restrict__ lwo, const float* __restrict__ lbo,
    float* __restrict__ outp) {
  __shared__ alignas(16) unsigned short Sm[2 * 128 * 64];  // As|Bs, reused as Rs
  unsigned short* As = Sm;
  unsigned short* Bs = Sm + 128 * 64;
  unsigned short* Rs = Sm;  // 128 x 128 bf16 residual, chunk-swizzled
  __shared__ float part[4][2];

  int p = blockIdx.x;
  int cpx = gridDim.x >> 3;
  int v = (p & 7) * cpx + (p >> 3);
  int bb = v >> 9;
  int t = v & 511;

  int tid = threadIdx.x;
  int w = tid >> 6, lane = tid & 63;
  int wr = w >> 1, wc = w & 1;
  int lr = lane & 15, kg = lane >> 4;

  const unsigned short* pvb = pv + (size_t)bb * H * T * EV + (size_t)t * EV;

  f32x4 acc[4][4] = {};
  for (int k0 = 0; k0 < 128; k0 += 64) {
#pragma unroll
    for (int j = 0; j < 4; ++j) {
      int ch = j * 256 + tid;
      int r = ch >> 3;
      int c0 = (ch & 7) * 8;
      gl_lds16(Wo2 + (size_t)r * 128 + k0 + c0, &As[ch * 8]);
      int cc = k0 + c0;
      int h = cc >> 5, dv0 = cc & 31;
      gl_lds16(pvb + (size_t)h * T * EV + (size_t)r * 32 + dv0, &Bs[ch * 8]);
    }
    __syncthreads();
#pragma unroll
    for (int ks = 0; ks < 2; ++ks) {
      bf16x8 af[4], bf[4];
#pragma unroll
      for (int m = 0; m < 4; ++m)
        af[m] = *reinterpret_cast<const bf16x8*>(
            &As[(wr * 64 + m * 16 + lr) * 64 + ks * 32 + kg * 8]);
#pragma unroll
      for (int n = 0; n < 4; ++n)
        bf[n] = *reinterpret_cast<const bf16x8*>(
            &Bs[(wc * 64 + n * 16 + lr) * 64 + ks * 32 + kg * 8]);
#pragma unroll
      for (int m = 0; m < 4; ++m)
#pragma unroll
        for (int n = 0; n < 4; ++n)
          acc[m][n] = __builtin_amdgcn_mfma_f32_16x16x32_bf16(af[m], bf[n], acc[m][n], 0, 0, 0);
    }
    __syncthreads();
  }

  // Stage residual: xT slab row f (128 bf16 of d). 2048 16B chunks.
  // LDS slot s of row f holds global chunk s^(f&15)  (pre-swizzled source;
  // gl_lds dest stays linear -- rule #21).
  const unsigned short* xTb = xT + ((size_t)bb * 65536 + (size_t)t * 128) * 128;
#pragma unroll
  for (int j = 0; j < 8; ++j) {
    int ch = j * 256 + tid;
    int f = ch >> 4;
    int s = ch & 15;
    gl_lds16(xTb + (size_t)f * 128 + ((s ^ (f & 15)) * 8), &Rs[ch * 8]);
  }

  float aO = ao[0];
  float s = 0.f, s2 = 0.f;
#pragma unroll
  for (int m = 0; m < 4; ++m)
#pragma unroll
    for (int j = 0; j < 4; ++j) {
      int d = wr * 64 + m * 16 + kg * 4 + j;
      float bi = bo[d];
#pragma unroll
      for (int n = 0; n < 4; ++n) {
        float val = acc[m][n][j] + bi;
        val = val >= 0.f ? val : aO * val;
        acc[m][n][j] = val;
        s += val;
        s2 += val * val;
      }
    }
#pragma unroll
  for (int off = 32; off >= 1; off >>= 1) {
    s += __shfl_xor(s, off, 64);
    s2 += __shfl_xor(s2, off, 64);
  }
  if (lane == 0) { part[w][0] = s; part[w][1] = s2; }
  __syncthreads();  // part visible + vmcnt drained -> Rs ready
  float S = part[0][0] + part[1][0] + part[2][0] + part[3][0];
  float S2 = part[0][1] + part[1][1] + part[2][1] + part[3][1];
  const float invN = 1.f / 16384.f;
  float mu = S * invN;
  float var = S2 * invN - mu * mu;
  float rstd = rsqrtf(var + EPS);
#pragma unroll
  for (int m = 0; m < 4; ++m) {
    int d0 = wr * 64 + m * 16 + kg * 4;
#pragma unroll
    for (int n = 0; n < 4; ++n) {
      int f = wc * 64 + n * 16 + lr;
      // residual: Rs addr = f*128 + ((d>>3)^(f&15))*8 + (d&7); d0..d0+3 share granule
      int ra = f * 128 + (((d0 >> 3) ^ (f & 15)) << 3) + (d0 & 7);
      ushort4 rv = *reinterpret_cast<const ushort4*>(&Rs[ra]);
      const unsigned short* rp = reinterpret_cast<const unsigned short*>(&rv);
#pragma unroll
      for (int j = 0; j < 4; ++j) {
        int d = d0 + j;
        float val = (acc[m][n][j] - mu) * rstd * lwo[d * 128 + f] + lbo[d * 128 + f];
        size_t xi = (((size_t)bb * C + d) * T + t) * F + f;
        outp[xi] = val + bf2f(rp[j]);
      }
    }
  }
}

// ---------------------------------------------------------------------------
extern "C" void kernel_launch(void* const* d_in, const int* in_sizes, int n_in,
                              void* d_out, int out_size, void* d_ws, size_t ws_size,
                              hipStream_t stream) {
  const float* x   = (const float*)d_in[0];
  const float* Wq  = (const float*)d_in[1];
  const float* bq  = (const float*)d_in[2];
  const float* aq  = (const float*)d_in[3];
  const float* lwq = (const float*)d_in[4];
  const float* lbq = (const float*)d_in[5];
  const float* Wk  = (const float*)d_in[6];
  const float* bk_ = (const float*)d_in[7];
  const float* ak  = (const float*)d_in[8];
  const float* lwk = (const float*)d_in[9];
  const float* lbk = (const float*)d_in[10];
  const float* Wv  = (const float*)d_in[11];
  const float* bv  = (const float*)d_in[12];
  const float* av  = (const float*)d_in[13];
  const float* lwv = (const float*)d_in[14];
  const float* lbv = (const float*)d_in[15];
  const float* Wo  = (const float*)d_in[16];
  const float* bo  = (const float*)d_in[17];
  const float* ao  = (const float*)d_in[18];
  const float* lwo = (const float*)d_in[19];
  const float* lbo = (const float*)d_in[20];
  float* outp = (float*)d_out;

  char* ws = (char*)d_ws;
  // phase-1: qf 0..128M, kf 128..256M, vf 256..320M, xT 320..384M (ALIVE to end)
  unsigned short* qfp = (unsigned short*)(ws);
  unsigned short* kfp = (unsigned short*)(ws + 134217728ull);
  unsigned short* vfp = (unsigned short*)(ws + 268435456ull);
  unsigned short* xT  = (unsigned short*)(ws + 335544320ull);
  // Wo2 survives to outproj; proj-only weights are overlaid by atnP later.
  unsigned short* Wo2   = (unsigned short*)(ws + 402653184ull);  // 32 KB
  unsigned short* Wall  = (unsigned short*)(ws + 402685952ull);  // 160 KB (dead after proj)
  float*          lwall = (float*)(ws + 402849792ull);           // 320 KB (dead after proj)
  float*          lball = (float*)(ws + 403177472ull);           // 320 KB (dead after proj)
  float*          ball  = (float*)(ws + 403505152ull);           // 4 KB
  float*          aall  = (float*)(ws + 403509248ull);           // 4 KB
  float*          lwI   = (float*)(ws + 403513344ull);           // 64 KB
  float*          lbI   = (float*)(ws + 403578880ull);           // 64 KB
  // atnP fp16 (kchunks=2, 16.8 MB) overlays dead proj weights: 402685952..419463168
  unsigned short* atnP = (unsigned short*)(ws + 402685952ull);
  // phase-2 reuse
  unsigned short* atnb = (unsigned short*)(ws);                  //  8 MB (ex-qf)
  unsigned short* vfT  = (unsigned short*)(ws + 134217728ull);   // 64 MB (ex-kf)
  unsigned short* pvp  = (unsigned short*)(ws + 268435456ull);   // 64 MB (ex-vf)

  prep_kernel<<<320, 256, 0, stream>>>(Wq, Wk, Wv, Wo, bq, bk_, bv, aq, ak, av,
                                       lwq, lwk, lwv, lbq, lbk, lbv,
                                       Wall, Wo2, ball, aall, lwall, lball,
                                       lwI, lbI);

  xT_kernel<<<2048, 256, 0, stream>>>(x, xT);

  // R7-proven projection (190 us)
  proj_gemm_kernel<<<10240, 256, 0, stream>>>(Wall, xT, ball, aall,
                                              lwall, lball, lwI, lbI,
                                              qfp, kfp, vfp);

  // logits K-split x2, fp16 partials into atnP[kc][bh][512][512]
  gemm_bt_kernel<2><<<512, 256, 0, stream>>>(
      qfp, kfp, atnP, 512, 512, 8192, 0.011048543456039806f, 4, 4, 2, 16);

  // vf -> vfT (into ex-kf; kf dead after logits)
  transpose_v_kernel<<<8192, 256, 0, stream>>>(vfp, vfT);

  // softmax: sum 2 fp16 partials -> bf16 probs (into ex-qf)
  softmax_kernel<<<8192, 64, 0, stream>>>(atnP, atnb, 2);

  // PV: O = P V  (M=512, N=4096, K=512), bf16 out; e' = f*32+dv layout
  gemm_bt_kernel<1><<<2048, 256, 0, stream>>>(
      atnb, vfT, pvp, 512, 4096, 512, 1.0f, 4, 32, 1, 16);

  // out-projection: B from pv, residual from bf16 xT (x fp32 not re-read)
  outproj_gemm_kernel<<<2048, 256, 0, stream>>>(Wo2, pvp, xT, bo, ao, lwo, lbo, outp);
}